// Round 4
// baseline (387.051 us; speedup 1.0000x reference)
//
#include <hip/hip_runtime.h>

#define DIM 128
#define LN_EPS 1e-5f

typedef __attribute__((ext_vector_type(8))) short bf16x8;
typedef __attribute__((ext_vector_type(4))) float f32x4;

static __device__ __forceinline__ unsigned short f2bf(float f) {
    unsigned int u = __builtin_bit_cast(unsigned int, f);
    u += 0x7fffu + ((u >> 16) & 1u);  // round-to-nearest-even
    return (unsigned short)(u >> 16);
}
static __device__ __forceinline__ float bf2f_lo(unsigned int u) {
    return __builtin_bit_cast(float, u << 16);
}
static __device__ __forceinline__ float bf2f_hi(unsigned int u) {
    return __builtin_bit_cast(float, u & 0xffff0000u);
}

// --------------------- fused: x fp32->bf16, W transpose+cvt, degree count
// blocks [0, nx4b): convert x (float4 -> bf16x4 per thread)
// blocks [nx4b, nx4b+128): transpose+convert W1,W2
// blocks [nx4b+128, ...): degree count (atomics into counts)
__global__ __launch_bounds__(256) void cvt_count_kernel(const float* __restrict__ X,
                                                        unsigned short* __restrict__ Y, int n4,
                                                        int nx4b,
                                                        const float* __restrict__ W1,
                                                        const float* __restrict__ W2,
                                                        unsigned short* __restrict__ Wt1,
                                                        unsigned short* __restrict__ Wt2,
                                                        const int* __restrict__ dst,
                                                        int* __restrict__ counts, int E) {
    int b = blockIdx.x;
    if (b < nx4b) {
        int i = b * 256 + threadIdx.x;
        if (i < n4) {
            float4 v = ((const float4*)X)[i];
            ushort4 o;
            o.x = f2bf(v.x); o.y = f2bf(v.y); o.z = f2bf(v.z); o.w = f2bf(v.w);
            ((ushort4*)Y)[i] = o;
        }
    } else if (b < nx4b + 128) {
        int elem = (b - nx4b) * 256 + threadIdx.x;  // [0, 32768)
        int which = elem >> 14;
        int rest = elem & 16383;
        int c = rest >> 7;
        int k = rest & 127;
        const float* W = which ? W2 : W1;
        unsigned short* Wt = which ? Wt2 : Wt1;
        Wt[c * 128 + k] = f2bf(W[k * 128 + c]);
    } else {
        int e = (b - nx4b - 128) * 256 + threadIdx.x;
        if (e < E) atomicAdd(&counts[dst[e]], 1);
    }
}

// ------------------------------------------------- scan pass 1 (+dinv compute)
__global__ __launch_bounds__(256) void scan1_kernel(const int* __restrict__ counts,
                                                    int* __restrict__ tmp,
                                                    int* __restrict__ bsums,
                                                    float* __restrict__ dinv, int n) {
    __shared__ int ts[256];
    int tid = threadIdx.x;
    int base = blockIdx.x * 1024 + tid * 4;
    int v[4];
#pragma unroll
    for (int j = 0; j < 4; ++j) {
        int i = base + j;
        v[j] = (i < n) ? counts[i] : 0;
        if (i < n) dinv[i] = rsqrtf((float)(v[j] + 1));  // +1 self-loop
    }
    int s = v[0] + v[1] + v[2] + v[3];
    ts[tid] = s;
    __syncthreads();
    for (int off = 1; off < 256; off <<= 1) {
        int t2 = (tid >= off) ? ts[tid - off] : 0;
        __syncthreads();
        ts[tid] += t2;
        __syncthreads();
    }
    int excl = ts[tid] - s;
    int pre = excl;
#pragma unroll
    for (int j = 0; j < 4; ++j) {
        int i = base + j;
        if (i < n) tmp[i] = pre;
        pre += v[j];
    }
    if (tid == 255) bsums[blockIdx.x] = ts[255];
}

// ------------------------------------------------- scan pass 2 (block totals)
__global__ __launch_bounds__(64) void scan2_kernel(int* __restrict__ bsums, int nb) {
    int lane = threadIdx.x;
    int v = (lane < nb) ? bsums[lane] : 0;
    int x = v;
#pragma unroll
    for (int off = 1; off < 64; off <<= 1) {
        int y = __shfl_up(x, off);
        if (lane >= off) x += y;
    }
    if (lane < nb) bsums[lane] = x - v;  // exclusive
}

// ------------------------------------------------- scan pass 3 (apply offsets)
__global__ __launch_bounds__(256) void scan3_kernel(const int* __restrict__ tmp,
                                                    const int* __restrict__ bsums,
                                                    int* __restrict__ rowptr,
                                                    int* __restrict__ cursor, int n, int E) {
    int base = blockIdx.x * 1024 + threadIdx.x * 4;
    int add = bsums[blockIdx.x];
#pragma unroll
    for (int j = 0; j < 4; ++j) {
        int i = base + j;
        if (i < n) {
            int val = tmp[i] + add;
            rowptr[i] = val;
            cursor[i] = val;
        }
    }
    if (blockIdx.x == 0 && threadIdx.x == 0) rowptr[n] = E;
}

// ---------------------------------------------------------------- CSR fill
__global__ __launch_bounds__(256) void fill_kernel(const int* __restrict__ src,
                                                   const int* __restrict__ dst,
                                                   int* __restrict__ cursor,
                                                   int* __restrict__ colsrc, int E) {
    int e = blockIdx.x * 256 + threadIdx.x;
    if (e < E) {
        int p = atomicAdd(&cursor[dst[e]], 1);
        colsrc[p] = src[e];
    }
}

// ---------------------------------------------------------------- MFMA GEMM
// H[r][c] = dinv[r] * sum_k A[r][k] * W[k][c], A bf16, output bf16.
// Bt[c][k] = W[k][c] (bf16). One wave per 16x128 output tile.
__global__ __launch_bounds__(256) void gemm_mfma_kernel(const unsigned short* __restrict__ A,
                                                        const unsigned short* __restrict__ Bt,
                                                        const float* __restrict__ dinv,
                                                        unsigned short* __restrict__ H,
                                                        int n, int ntiles) {
    int wid = threadIdx.x >> 6;
    int lane = threadIdx.x & 63;
    int tile = blockIdx.x * 4 + wid;
    if (tile >= ntiles) return;
    int r0 = tile * 16;
    int mrow = lane & 15;
    int kgrp = lane >> 4;  // 0..3

    int arow_i = r0 + mrow;
    if (arow_i > n - 1) arow_i = n - 1;
    const unsigned short* arow = A + (size_t)arow_i * DIM + kgrp * 8;

    f32x4 acc[8];
#pragma unroll
    for (int t = 0; t < 8; ++t) acc[t] = (f32x4){0.f, 0.f, 0.f, 0.f};

#pragma unroll
    for (int kc = 0; kc < 4; ++kc) {
        bf16x8 af = *(const bf16x8*)(arow + kc * 32);
#pragma unroll
        for (int t = 0; t < 8; ++t) {
            bf16x8 bfv = *(const bf16x8*)(Bt + (size_t)(t * 16 + mrow) * DIM + kc * 32 + kgrp * 8);
            acc[t] = __builtin_amdgcn_mfma_f32_16x16x32_bf16(af, bfv, acc[t], 0, 0, 0);
        }
    }

    // D layout: row = r0 + kgrp*4 + reg, col = t*16 + mrow
    float dv[4];
#pragma unroll
    for (int reg = 0; reg < 4; ++reg) {
        int rr = r0 + kgrp * 4 + reg;
        dv[reg] = (rr < n) ? dinv[rr] : 0.f;
    }
#pragma unroll
    for (int t = 0; t < 8; ++t) {
#pragma unroll
        for (int reg = 0; reg < 4; ++reg) {
            int row = r0 + kgrp * 4 + reg;
            if (row < n) {
                int col = t * 16 + mrow;
                H[(size_t)row * DIM + col] = f2bf(acc[t][reg] * dv[reg]);
            }
        }
    }
}

// ----------------------------------------- column-quartered gather (agg only)
// Quarter q of row s = bytes [s*256 + q*64, +64) = one 64B L2 line.
// A quarter's working set = 3.2 MB -> fits per-XCD L2.
// Wave = 4 nodes x 16 lanes; lane t of group g reads uint (2 cols) of node r_g.
// q = blockIdx.x / blocksPerQ (slowest index -> resident blocks share quarter).
__global__ __launch_bounds__(256) void gatherq_kernel(const int* __restrict__ rowptr,
                                                      const int* __restrict__ colsrc,
                                                      const unsigned int* __restrict__ H32,
                                                      unsigned int* __restrict__ agg32,
                                                      int n, int blocksPerQ, int E) {
    int q = blockIdx.x / blocksPerQ;
    int b = blockIdx.x - q * blocksPerQ;
    int wid = threadIdx.x >> 6;
    int lane = threadIdx.x & 63;
    int g = lane >> 4;   // group 0..3
    int t = lane & 15;
    int r = (b * 4 + wid) * 4 + g;
    int valid = (r < n);
    int rc = valid ? r : (n - 1);

    int p0 = rowptr[rc];
    int p1 = rowptr[rc + 1];
    int deg = valid ? (p1 - p0) : 0;

    // wave-max degree (uniform loop count; all 16 lanes of a group agree)
    int maxd = deg;
    maxd = max(maxd, __shfl_xor(maxd, 16));
    maxd = max(maxd, __shfl_xor(maxd, 32));

    int qoff = q * 16 + t;

    // self-loop term
    unsigned int hv = H32[(size_t)rc * 64 + qoff];
    float ax = bf2f_lo(hv), ay = bf2f_hi(hv);

    int Emax = E - 1;
    int gi = p0 < Emax ? p0 : Emax;
    int idx_next = colsrc[gi];  // prefetch edge 0

    for (int j = 0; j < maxd; ++j) {
        int cur = idx_next;
        // prefetch next edge index (clamped to a valid slot)
        int gn = p0 + j + 1;
        int hi = p1 - 1;
        gn = gn < hi ? gn : hi;
        gn = gn > 0 ? gn : 0;
        gn = gn < Emax ? gn : Emax;
        idx_next = colsrc[gn];
        unsigned int h = H32[(size_t)cur * 64 + qoff];
        int act = (j < deg);
        ax += act ? bf2f_lo(h) : 0.f;
        ay += act ? bf2f_hi(h) : 0.f;
    }

    if (valid) {
        unsigned int pk = (unsigned int)f2bf(ax) | ((unsigned int)f2bf(ay) << 16);
        agg32[(size_t)r * 64 + qoff] = pk;
    }
}

// ------------------------------------------- dinv*agg + bias + LN (+ReLU)
// one wave per node; lane owns cols (2*lane, 2*lane+1) as packed bf16 uint.
__global__ __launch_bounds__(256) void ln_kernel(const unsigned int* __restrict__ agg32,
                                                 const float* __restrict__ dinv,
                                                 const float* __restrict__ bias,
                                                 const float* __restrict__ gamma,
                                                 const float* __restrict__ beta,
                                                 unsigned int* __restrict__ out_bf,
                                                 float* __restrict__ out_f,
                                                 int n, int relu) {
    int wid = threadIdx.x >> 6;
    int lane = threadIdx.x & 63;
    int r = blockIdx.x * 4 + wid;
    if (r >= n) return;

    float di = dinv[r];
    float2 bb = ((const float2*)bias)[lane];
    float2 gg = ((const float2*)gamma)[lane];
    float2 be = ((const float2*)beta)[lane];

    unsigned int av = agg32[(size_t)r * 64 + lane];
    float vx = bf2f_lo(av) * di + bb.x;
    float vy = bf2f_hi(av) * di + bb.y;

    float s1 = vx + vy;
    float s2 = vx * vx + vy * vy;
#pragma unroll
    for (int off = 32; off > 0; off >>= 1) {
        s1 += __shfl_xor(s1, off);
        s2 += __shfl_xor(s2, off);
    }
    float mu = s1 * (1.f / 128.f);
    float var = s2 * (1.f / 128.f) - mu * mu;
    float rstd = rsqrtf(var + LN_EPS);

    float ox = (vx - mu) * rstd * gg.x + be.x;
    float oy = (vy - mu) * rstd * gg.y + be.y;
    if (relu) {
        ox = fmaxf(ox, 0.f);
        oy = fmaxf(oy, 0.f);
    }
    if (out_bf) {
        unsigned int pk = (unsigned int)f2bf(ox) | ((unsigned int)f2bf(oy) << 16);
        out_bf[(size_t)r * 64 + lane] = pk;
    } else {
        ((float2*)out_f)[(size_t)r * 64 + lane] = make_float2(ox, oy);
    }
}

// =============================================================================
extern "C" void kernel_launch(void* const* d_in, const int* in_sizes, int n_in,
                              void* d_out, int out_size, void* d_ws, size_t ws_size,
                              hipStream_t stream) {
    const float* x   = (const float*)d_in[0];
    const int*   ei  = (const int*)d_in[1];
    const float* W1  = (const float*)d_in[2];
    const float* b1  = (const float*)d_in[3];
    const float* g1  = (const float*)d_in[4];
    const float* be1 = (const float*)d_in[5];
    const float* W2  = (const float*)d_in[6];
    const float* b2  = (const float*)d_in[7];
    const float* g2  = (const float*)d_in[8];
    const float* be2 = (const float*)d_in[9];

    int n = in_sizes[0] / DIM;   // 50000
    int E = in_sizes[1] / 2;     // 600000
    const int* src = ei;
    const int* dst = ei + E;

    char* wp = (char*)d_ws;
    auto alloc = [&](size_t bytes) {
        void* p = (void*)wp;
        wp += (bytes + 255) & ~(size_t)255;
        return p;
    };
    float*          dinv   = (float*)alloc((size_t)n * 4);
    int*            counts = (int*)alloc((size_t)n * 4);
    int*            tmp    = (int*)alloc((size_t)n * 4);
    int*            rowptr = (int*)alloc((size_t)(n + 1) * 4);
    int*            cursor = (int*)alloc((size_t)n * 4);
    int*            bsums  = (int*)alloc(64 * 4);
    int*            colsrc = (int*)alloc((size_t)E * 4);
    unsigned short* xb     = (unsigned short*)alloc((size_t)n * DIM * 2);
    unsigned short* Wt1    = (unsigned short*)alloc(128 * 128 * 2);
    unsigned short* Wt2    = (unsigned short*)alloc(128 * 128 * 2);
    unsigned short* H      = (unsigned short*)alloc((size_t)n * DIM * 2);
    unsigned short* Agg    = (unsigned short*)alloc((size_t)n * DIM * 2);
    unsigned short* Y1     = (unsigned short*)alloc((size_t)n * DIM * 2);

    hipMemsetAsync(counts, 0, (size_t)n * 4, stream);

    // --- conversions + degree count (one dispatch) ---
    int n4 = n * DIM / 4;
    int nx4b = (n4 + 255) / 256;
    int gE = (E + 255) / 256;
    cvt_count_kernel<<<nx4b + 128 + gE, 256, 0, stream>>>(x, xb, n4, nx4b, W1, W2, Wt1, Wt2,
                                                          dst, counts, E);

    // --- CSR build ---
    int nb1 = (n + 1023) / 1024;  // 49 for n=50000 (must be <= 64)
    scan1_kernel<<<nb1, 256, 0, stream>>>(counts, tmp, bsums, dinv, n);
    scan2_kernel<<<1, 64, 0, stream>>>(bsums, nb1);
    scan3_kernel<<<nb1, 256, 0, stream>>>(tmp, bsums, rowptr, cursor, n, E);
    fill_kernel<<<gE, 256, 0, stream>>>(src, dst, cursor, colsrc, E);

    int ntiles = (n + 15) / 16;
    int gG = (ntiles + 3) / 4;
    int blocksPerQ = (n + 15) / 16;  // 16 nodes per block (4 waves x 4 nodes)
    int gQ = blocksPerQ * 4;
    int gL = (n + 3) / 4;

    // --- layer 1 ---
    gemm_mfma_kernel<<<gG, 256, 0, stream>>>(xb, Wt1, dinv, H, n, ntiles);
    gatherq_kernel<<<gQ, 256, 0, stream>>>(rowptr, colsrc, (const unsigned int*)H,
                                           (unsigned int*)Agg, n, blocksPerQ, E);
    ln_kernel<<<gL, 256, 0, stream>>>((const unsigned int*)Agg, dinv, b1, g1, be1,
                                      (unsigned int*)Y1, nullptr, n, 1);

    // --- layer 2 ---
    gemm_mfma_kernel<<<gG, 256, 0, stream>>>(Y1, Wt2, dinv, H, n, ntiles);
    gatherq_kernel<<<gQ, 256, 0, stream>>>(rowptr, colsrc, (const unsigned int*)H,
                                           (unsigned int*)Agg, n, blocksPerQ, E);
    ln_kernel<<<gL, 256, 0, stream>>>((const unsigned int*)Agg, dinv, b2, g2, be2,
                                      nullptr, (float*)d_out, n, 0);
}

// Round 5
// 370.480 us; speedup vs baseline: 1.0447x; 1.0447x over previous
//
#include <hip/hip_runtime.h>

#define DIM 128
#define LN_EPS 1e-5f

typedef __attribute__((ext_vector_type(8))) short bf16x8;
typedef __attribute__((ext_vector_type(4))) float f32x4;

static __device__ __forceinline__ unsigned short f2bf(float f) {
    unsigned int u = __builtin_bit_cast(unsigned int, f);
    u += 0x7fffu + ((u >> 16) & 1u);  // round-to-nearest-even
    return (unsigned short)(u >> 16);
}
static __device__ __forceinline__ float bf2f_lo(unsigned int u) {
    return __builtin_bit_cast(float, u << 16);
}
static __device__ __forceinline__ float bf2f_hi(unsigned int u) {
    return __builtin_bit_cast(float, u & 0xffff0000u);
}

// --------------------- fused: x fp32->bf16, W transpose+cvt, degree count
__global__ __launch_bounds__(256) void cvt_count_kernel(const float* __restrict__ X,
                                                        unsigned short* __restrict__ Y, int n4,
                                                        int nx4b,
                                                        const float* __restrict__ W1,
                                                        const float* __restrict__ W2,
                                                        unsigned short* __restrict__ Wt1,
                                                        unsigned short* __restrict__ Wt2,
                                                        const int* __restrict__ dst,
                                                        int* __restrict__ counts, int E) {
    int b = blockIdx.x;
    if (b < nx4b) {
        int i = b * 256 + threadIdx.x;
        if (i < n4) {
            float4 v = ((const float4*)X)[i];
            ushort4 o;
            o.x = f2bf(v.x); o.y = f2bf(v.y); o.z = f2bf(v.z); o.w = f2bf(v.w);
            ((ushort4*)Y)[i] = o;
        }
    } else if (b < nx4b + 128) {
        int elem = (b - nx4b) * 256 + threadIdx.x;  // [0, 32768)
        int which = elem >> 14;
        int rest = elem & 16383;
        int c = rest >> 7;
        int k = rest & 127;
        const float* W = which ? W2 : W1;
        unsigned short* Wt = which ? Wt2 : Wt1;
        Wt[c * 128 + k] = f2bf(W[k * 128 + c]);
    } else {
        int e = (b - nx4b - 128) * 256 + threadIdx.x;
        if (e < E) atomicAdd(&counts[dst[e]], 1);
    }
}

// ------------------------------------------------- scan pass 1 (+dinv compute)
__global__ __launch_bounds__(256) void scan1_kernel(const int* __restrict__ counts,
                                                    int* __restrict__ tmp,
                                                    int* __restrict__ bsums,
                                                    float* __restrict__ dinv, int n) {
    __shared__ int ts[256];
    int tid = threadIdx.x;
    int base = blockIdx.x * 1024 + tid * 4;
    int v[4];
#pragma unroll
    for (int j = 0; j < 4; ++j) {
        int i = base + j;
        v[j] = (i < n) ? counts[i] : 0;
        if (i < n) dinv[i] = rsqrtf((float)(v[j] + 1));  // +1 self-loop
    }
    int s = v[0] + v[1] + v[2] + v[3];
    ts[tid] = s;
    __syncthreads();
    for (int off = 1; off < 256; off <<= 1) {
        int t2 = (tid >= off) ? ts[tid - off] : 0;
        __syncthreads();
        ts[tid] += t2;
        __syncthreads();
    }
    int excl = ts[tid] - s;
    int pre = excl;
#pragma unroll
    for (int j = 0; j < 4; ++j) {
        int i = base + j;
        if (i < n) tmp[i] = pre;
        pre += v[j];
    }
    if (tid == 255) bsums[blockIdx.x] = ts[255];
}

// ------------------------------------------------- scan pass 2 (block totals)
__global__ __launch_bounds__(64) void scan2_kernel(int* __restrict__ bsums, int nb) {
    int lane = threadIdx.x;
    int v = (lane < nb) ? bsums[lane] : 0;
    int x = v;
#pragma unroll
    for (int off = 1; off < 64; off <<= 1) {
        int y = __shfl_up(x, off);
        if (lane >= off) x += y;
    }
    if (lane < nb) bsums[lane] = x - v;  // exclusive
}

// ------------------------------------------------- scan pass 3 (apply offsets)
__global__ __launch_bounds__(256) void scan3_kernel(const int* __restrict__ tmp,
                                                    const int* __restrict__ bsums,
                                                    int* __restrict__ rowptr,
                                                    int* __restrict__ cursor, int n, int E) {
    int base = blockIdx.x * 1024 + threadIdx.x * 4;
    int add = bsums[blockIdx.x];
#pragma unroll
    for (int j = 0; j < 4; ++j) {
        int i = base + j;
        if (i < n) {
            int val = tmp[i] + add;
            rowptr[i] = val;
            cursor[i] = val;
        }
    }
    if (blockIdx.x == 0 && threadIdx.x == 0) rowptr[n] = E;
}

// ---------------------------------------------------------------- CSR fill
// colsrc is ushort (node ids < 65536) to halve replayed index traffic.
__global__ __launch_bounds__(256) void fill_kernel(const int* __restrict__ src,
                                                   const int* __restrict__ dst,
                                                   int* __restrict__ cursor,
                                                   unsigned short* __restrict__ colsrc, int E) {
    int e = blockIdx.x * 256 + threadIdx.x;
    if (e < E) {
        int p = atomicAdd(&cursor[dst[e]], 1);
        colsrc[p] = (unsigned short)src[e];
    }
}

// ---------------------------------------------------------------- MFMA GEMM
// H stored PLANE-MAJOR: plane q (cols [q*32,q*32+32)) is contiguous,
// row s of plane q at ushort offset (q*n + s)*32. One 128B L2 line covers
// two consecutive rows of the SAME plane -> per-plane L2 footprint 3.2 MB.
__global__ __launch_bounds__(256) void gemm_mfma_kernel(const unsigned short* __restrict__ A,
                                                        const unsigned short* __restrict__ Bt,
                                                        const float* __restrict__ dinv,
                                                        unsigned short* __restrict__ H,
                                                        int n, int ntiles) {
    int wid = threadIdx.x >> 6;
    int lane = threadIdx.x & 63;
    int tile = blockIdx.x * 4 + wid;
    if (tile >= ntiles) return;
    int r0 = tile * 16;
    int mrow = lane & 15;
    int kgrp = lane >> 4;  // 0..3

    int arow_i = r0 + mrow;
    if (arow_i > n - 1) arow_i = n - 1;
    const unsigned short* arow = A + (size_t)arow_i * DIM + kgrp * 8;

    f32x4 acc[8];
#pragma unroll
    for (int t = 0; t < 8; ++t) acc[t] = (f32x4){0.f, 0.f, 0.f, 0.f};

#pragma unroll
    for (int kc = 0; kc < 4; ++kc) {
        bf16x8 af = *(const bf16x8*)(arow + kc * 32);
#pragma unroll
        for (int t = 0; t < 8; ++t) {
            bf16x8 bfv = *(const bf16x8*)(Bt + (size_t)(t * 16 + mrow) * DIM + kc * 32 + kgrp * 8);
            acc[t] = __builtin_amdgcn_mfma_f32_16x16x32_bf16(af, bfv, acc[t], 0, 0, 0);
        }
    }

    // D layout: row = r0 + kgrp*4 + reg, col = t*16 + mrow
    // plane q = t>>1 ; within-plane col c = (t&1)*16 + mrow
    float dv[4];
#pragma unroll
    for (int reg = 0; reg < 4; ++reg) {
        int rr = r0 + kgrp * 4 + reg;
        dv[reg] = (rr < n) ? dinv[rr] : 0.f;
    }
#pragma unroll
    for (int t = 0; t < 8; ++t) {
        int q = t >> 1;
        int c = (t & 1) * 16 + mrow;
#pragma unroll
        for (int reg = 0; reg < 4; ++reg) {
            int row = r0 + kgrp * 4 + reg;
            if (row < n) {
                H[((size_t)q * n + row) * 32 + c] = f2bf(acc[t][reg] * dv[reg]);
            }
        }
    }
}

// ----------------------------------------- plane-major quartered gather
// Plane q working set = n*64B = 3.2 MB -> resident in each XCD's 4 MiB L2.
// Wave = 4 nodes x 16 lanes; q = blockIdx.x / blocksPerQ (slowest index).
__global__ __launch_bounds__(256) void gatherq_kernel(const int* __restrict__ rowptr,
                                                      const unsigned short* __restrict__ colsrc,
                                                      const unsigned int* __restrict__ H32,
                                                      unsigned int* __restrict__ agg32,
                                                      int n, int blocksPerQ, int E) {
    int q = blockIdx.x / blocksPerQ;
    int b = blockIdx.x - q * blocksPerQ;
    int wid = threadIdx.x >> 6;
    int lane = threadIdx.x & 63;
    int g = lane >> 4;   // group 0..3
    int t = lane & 15;
    int r = (b * 4 + wid) * 4 + g;
    int valid = (r < n);
    int rc = valid ? r : (n - 1);

    int p0 = rowptr[rc];
    int p1 = rowptr[rc + 1];
    int deg = valid ? (p1 - p0) : 0;

    // wave-max degree (uniform loop count)
    int maxd = deg;
    maxd = max(maxd, __shfl_xor(maxd, 16));
    maxd = max(maxd, __shfl_xor(maxd, 32));

    const unsigned int* Hq = H32 + (size_t)q * n * 16;

    // self-loop term (4 consecutive rows -> contiguous 256B per wave)
    unsigned int hv = Hq[(size_t)rc * 16 + t];
    float ax = bf2f_lo(hv), ay = bf2f_hi(hv);

    int Emax = E - 1;
    int gi = p0 < Emax ? p0 : Emax;
    int idx_next = colsrc[gi];  // prefetch edge 0

    for (int j = 0; j < maxd; ++j) {
        int cur = idx_next;
        int gn = p0 + j + 1;
        int hi = p1 - 1;
        gn = gn < hi ? gn : hi;
        gn = gn > 0 ? gn : 0;
        gn = gn < Emax ? gn : Emax;
        idx_next = colsrc[gn];
        unsigned int h = Hq[(size_t)cur * 16 + t];
        int act = (j < deg);
        ax += act ? bf2f_lo(h) : 0.f;
        ay += act ? bf2f_hi(h) : 0.f;
    }

    if (valid) {
        unsigned int pk = (unsigned int)f2bf(ax) | ((unsigned int)f2bf(ay) << 16);
        agg32[((size_t)q * n + r) * 16 + t] = pk;
    }
}

// ------------------------------------------- dinv*agg + bias + LN (+ReLU)
// one wave per node; agg is plane-major; lane = q*16 + t.
__global__ __launch_bounds__(256) void ln_kernel(const unsigned int* __restrict__ agg32,
                                                 const float* __restrict__ dinv,
                                                 const float* __restrict__ bias,
                                                 const float* __restrict__ gamma,
                                                 const float* __restrict__ beta,
                                                 unsigned int* __restrict__ out_bf,
                                                 float* __restrict__ out_f,
                                                 int n, int relu) {
    int wid = threadIdx.x >> 6;
    int lane = threadIdx.x & 63;
    int r = blockIdx.x * 4 + wid;
    if (r >= n) return;
    int q = lane >> 4;
    int t = lane & 15;

    float di = dinv[r];
    float2 bb = ((const float2*)bias)[lane];
    float2 gg = ((const float2*)gamma)[lane];
    float2 be = ((const float2*)beta)[lane];

    unsigned int av = agg32[((size_t)q * n + r) * 16 + t];
    float vx = bf2f_lo(av) * di + bb.x;
    float vy = bf2f_hi(av) * di + bb.y;

    float s1 = vx + vy;
    float s2 = vx * vx + vy * vy;
#pragma unroll
    for (int off = 32; off > 0; off >>= 1) {
        s1 += __shfl_xor(s1, off);
        s2 += __shfl_xor(s2, off);
    }
    float mu = s1 * (1.f / 128.f);
    float var = s2 * (1.f / 128.f) - mu * mu;
    float rstd = rsqrtf(var + LN_EPS);

    float ox = (vx - mu) * rstd * gg.x + be.x;
    float oy = (vy - mu) * rstd * gg.y + be.y;
    if (relu) {
        ox = fmaxf(ox, 0.f);
        oy = fmaxf(oy, 0.f);
    }
    // lane owns cols (2*lane, 2*lane+1) of row-major output
    if (out_bf) {
        unsigned int pk = (unsigned int)f2bf(ox) | ((unsigned int)f2bf(oy) << 16);
        out_bf[(size_t)r * 64 + lane] = pk;
    } else {
        ((float2*)out_f)[(size_t)r * 64 + lane] = make_float2(ox, oy);
    }
}

// =============================================================================
extern "C" void kernel_launch(void* const* d_in, const int* in_sizes, int n_in,
                              void* d_out, int out_size, void* d_ws, size_t ws_size,
                              hipStream_t stream) {
    const float* x   = (const float*)d_in[0];
    const int*   ei  = (const int*)d_in[1];
    const float* W1  = (const float*)d_in[2];
    const float* b1  = (const float*)d_in[3];
    const float* g1  = (const float*)d_in[4];
    const float* be1 = (const float*)d_in[5];
    const float* W2  = (const float*)d_in[6];
    const float* b2  = (const float*)d_in[7];
    const float* g2  = (const float*)d_in[8];
    const float* be2 = (const float*)d_in[9];

    int n = in_sizes[0] / DIM;   // 50000
    int E = in_sizes[1] / 2;     // 600000
    const int* src = ei;
    const int* dst = ei + E;

    char* wp = (char*)d_ws;
    auto alloc = [&](size_t bytes) {
        void* p = (void*)wp;
        wp += (bytes + 255) & ~(size_t)255;
        return p;
    };
    float*          dinv   = (float*)alloc((size_t)n * 4);
    int*            counts = (int*)alloc((size_t)n * 4);
    int*            tmp    = (int*)alloc((size_t)n * 4);
    int*            rowptr = (int*)alloc((size_t)(n + 1) * 4);
    int*            cursor = (int*)alloc((size_t)n * 4);
    int*            bsums  = (int*)alloc(64 * 4);
    unsigned short* colsrc = (unsigned short*)alloc((size_t)E * 2);
    unsigned short* xb     = (unsigned short*)alloc((size_t)n * DIM * 2);
    unsigned short* Wt1    = (unsigned short*)alloc(128 * 128 * 2);
    unsigned short* Wt2    = (unsigned short*)alloc(128 * 128 * 2);
    unsigned short* H      = (unsigned short*)alloc((size_t)n * DIM * 2);
    unsigned short* Agg    = (unsigned short*)alloc((size_t)n * DIM * 2);
    unsigned short* Y1     = (unsigned short*)alloc((size_t)n * DIM * 2);

    hipMemsetAsync(counts, 0, (size_t)n * 4, stream);

    // --- conversions + degree count (one dispatch) ---
    int n4 = n * DIM / 4;
    int nx4b = (n4 + 255) / 256;
    int gE = (E + 255) / 256;
    cvt_count_kernel<<<nx4b + 128 + gE, 256, 0, stream>>>(x, xb, n4, nx4b, W1, W2, Wt1, Wt2,
                                                          dst, counts, E);

    // --- CSR build ---
    int nb1 = (n + 1023) / 1024;  // 49 for n=50000 (must be <= 64)
    scan1_kernel<<<nb1, 256, 0, stream>>>(counts, tmp, bsums, dinv, n);
    scan2_kernel<<<1, 64, 0, stream>>>(bsums, nb1);
    scan3_kernel<<<nb1, 256, 0, stream>>>(tmp, bsums, rowptr, cursor, n, E);
    fill_kernel<<<gE, 256, 0, stream>>>(src, dst, cursor, colsrc, E);

    int ntiles = (n + 15) / 16;
    int gG = (ntiles + 3) / 4;
    int blocksPerQ = (n + 15) / 16;  // 16 nodes per block (4 waves x 4 nodes)
    int gQ = blocksPerQ * 4;
    int gL = (n + 3) / 4;

    // --- layer 1 ---
    gemm_mfma_kernel<<<gG, 256, 0, stream>>>(xb, Wt1, dinv, H, n, ntiles);
    gatherq_kernel<<<gQ, 256, 0, stream>>>(rowptr, colsrc, (const unsigned int*)H,
                                           (unsigned int*)Agg, n, blocksPerQ, E);
    ln_kernel<<<gL, 256, 0, stream>>>((const unsigned int*)Agg, dinv, b1, g1, be1,
                                      (unsigned int*)Y1, nullptr, n, 1);

    // --- layer 2 ---
    gemm_mfma_kernel<<<gG, 256, 0, stream>>>(Y1, Wt2, dinv, H, n, ntiles);
    gatherq_kernel<<<gQ, 256, 0, stream>>>(rowptr, colsrc, (const unsigned int*)H,
                                           (unsigned int*)Agg, n, blocksPerQ, E);
    ln_kernel<<<gL, 256, 0, stream>>>((const unsigned int*)Agg, dinv, b2, g2, be2,
                                      nullptr, (float*)d_out, n, 0);
}

// Round 6
// 265.410 us; speedup vs baseline: 1.4583x; 1.3959x over previous
//
#include <hip/hip_runtime.h>

#define DIM 128
#define LN_EPS 1e-5f

typedef __attribute__((ext_vector_type(8))) short bf16x8;
typedef __attribute__((ext_vector_type(4))) float f32x4;

static __device__ __forceinline__ unsigned short f2bf(float f) {
    unsigned int u = __builtin_bit_cast(unsigned int, f);
    u += 0x7fffu + ((u >> 16) & 1u);  // round-to-nearest-even
    return (unsigned short)(u >> 16);
}
static __device__ __forceinline__ float bf2f_lo(unsigned int u) {
    return __builtin_bit_cast(float, u << 16);
}
static __device__ __forceinline__ float bf2f_hi(unsigned int u) {
    return __builtin_bit_cast(float, u & 0xffff0000u);
}

// --------------------- fused: x fp32->bf16, W transpose+cvt, degree count
__global__ __launch_bounds__(256) void cvt_count_kernel(const float* __restrict__ X,
                                                        unsigned short* __restrict__ Y, int n4,
                                                        int nx4b,
                                                        const float* __restrict__ W1,
                                                        const float* __restrict__ W2,
                                                        unsigned short* __restrict__ Wt1,
                                                        unsigned short* __restrict__ Wt2,
                                                        const int* __restrict__ dst,
                                                        int* __restrict__ counts, int E) {
    int b = blockIdx.x;
    if (b < nx4b) {
        int i = b * 256 + threadIdx.x;
        if (i < n4) {
            float4 v = ((const float4*)X)[i];
            ushort4 o;
            o.x = f2bf(v.x); o.y = f2bf(v.y); o.z = f2bf(v.z); o.w = f2bf(v.w);
            ((ushort4*)Y)[i] = o;
        }
    } else if (b < nx4b + 128) {
        int elem = (b - nx4b) * 256 + threadIdx.x;  // [0, 32768)
        int which = elem >> 14;
        int rest = elem & 16383;
        int c = rest >> 7;
        int k = rest & 127;
        const float* W = which ? W2 : W1;
        unsigned short* Wt = which ? Wt2 : Wt1;
        Wt[c * 128 + k] = f2bf(W[k * 128 + c]);
    } else {
        int e = (b - nx4b - 128) * 256 + threadIdx.x;
        if (e < E) atomicAdd(&counts[dst[e]], 1);
    }
}

// ------------------------------------------------- scan pass 1 (+dinv compute)
__global__ __launch_bounds__(256) void scan1_kernel(const int* __restrict__ counts,
                                                    int* __restrict__ tmp,
                                                    int* __restrict__ bsums,
                                                    float* __restrict__ dinv, int n) {
    __shared__ int ts[256];
    int tid = threadIdx.x;
    int base = blockIdx.x * 1024 + tid * 4;
    int v[4];
#pragma unroll
    for (int j = 0; j < 4; ++j) {
        int i = base + j;
        v[j] = (i < n) ? counts[i] : 0;
        if (i < n) dinv[i] = rsqrtf((float)(v[j] + 1));  // +1 self-loop
    }
    int s = v[0] + v[1] + v[2] + v[3];
    ts[tid] = s;
    __syncthreads();
    for (int off = 1; off < 256; off <<= 1) {
        int t2 = (tid >= off) ? ts[tid - off] : 0;
        __syncthreads();
        ts[tid] += t2;
        __syncthreads();
    }
    int excl = ts[tid] - s;
    int pre = excl;
#pragma unroll
    for (int j = 0; j < 4; ++j) {
        int i = base + j;
        if (i < n) tmp[i] = pre;
        pre += v[j];
    }
    if (tid == 255) bsums[blockIdx.x] = ts[255];
}

// ------------------------------------------------- scan pass 2 (block totals)
__global__ __launch_bounds__(64) void scan2_kernel(int* __restrict__ bsums, int nb) {
    int lane = threadIdx.x;
    int v = (lane < nb) ? bsums[lane] : 0;
    int x = v;
#pragma unroll
    for (int off = 1; off < 64; off <<= 1) {
        int y = __shfl_up(x, off);
        if (lane >= off) x += y;
    }
    if (lane < nb) bsums[lane] = x - v;  // exclusive
}

// ------------------------------------------------- scan pass 3 (apply offsets)
__global__ __launch_bounds__(256) void scan3_kernel(const int* __restrict__ tmp,
                                                    const int* __restrict__ bsums,
                                                    int* __restrict__ rowptr,
                                                    int* __restrict__ cursor, int n, int E) {
    int base = blockIdx.x * 1024 + threadIdx.x * 4;
    int add = bsums[blockIdx.x];
#pragma unroll
    for (int j = 0; j < 4; ++j) {
        int i = base + j;
        if (i < n) {
            int val = tmp[i] + add;
            rowptr[i] = val;
            cursor[i] = val;
        }
    }
    if (blockIdx.x == 0 && threadIdx.x == 0) rowptr[n] = E;
}

// ---------------------------------------------------------------- CSR fill
__global__ __launch_bounds__(256) void fill_kernel(const int* __restrict__ src,
                                                   const int* __restrict__ dst,
                                                   int* __restrict__ cursor,
                                                   unsigned short* __restrict__ colsrc, int E) {
    int e = blockIdx.x * 256 + threadIdx.x;
    if (e < E) {
        int p = atomicAdd(&cursor[dst[e]], 1);
        colsrc[p] = (unsigned short)src[e];
    }
}

// ---------------------------------------------------------------- MFMA GEMM
// H[r][c] = dinv[r] * sum_k A[r][k] * W[k][c], A bf16, output bf16 row-major.
__global__ __launch_bounds__(256) void gemm_mfma_kernel(const unsigned short* __restrict__ A,
                                                        const unsigned short* __restrict__ Bt,
                                                        const float* __restrict__ dinv,
                                                        unsigned short* __restrict__ H,
                                                        int n, int ntiles) {
    int wid = threadIdx.x >> 6;
    int lane = threadIdx.x & 63;
    int tile = blockIdx.x * 4 + wid;
    if (tile >= ntiles) return;
    int r0 = tile * 16;
    int mrow = lane & 15;
    int kgrp = lane >> 4;  // 0..3

    int arow_i = r0 + mrow;
    if (arow_i > n - 1) arow_i = n - 1;
    const unsigned short* arow = A + (size_t)arow_i * DIM + kgrp * 8;

    f32x4 acc[8];
#pragma unroll
    for (int t = 0; t < 8; ++t) acc[t] = (f32x4){0.f, 0.f, 0.f, 0.f};

#pragma unroll
    for (int kc = 0; kc < 4; ++kc) {
        bf16x8 af = *(const bf16x8*)(arow + kc * 32);
#pragma unroll
        for (int t = 0; t < 8; ++t) {
            bf16x8 bfv = *(const bf16x8*)(Bt + (size_t)(t * 16 + mrow) * DIM + kc * 32 + kgrp * 8);
            acc[t] = __builtin_amdgcn_mfma_f32_16x16x32_bf16(af, bfv, acc[t], 0, 0, 0);
        }
    }

    // D layout: row = r0 + kgrp*4 + reg, col = t*16 + mrow
    float dv[4];
#pragma unroll
    for (int reg = 0; reg < 4; ++reg) {
        int rr = r0 + kgrp * 4 + reg;
        dv[reg] = (rr < n) ? dinv[rr] : 0.f;
    }
#pragma unroll
    for (int t = 0; t < 8; ++t) {
#pragma unroll
        for (int reg = 0; reg < 4; ++reg) {
            int row = r0 + kgrp * 4 + reg;
            if (row < n) {
                int col = t * 16 + mrow;
                H[(size_t)row * DIM + col] = f2bf(acc[t][reg] * dv[reg]);
            }
        }
    }
}

// ------------------- gather + bias + LayerNorm (+ReLU), branchless 16-batched
// One wave per node; lane owns cols (2*lane, 2*lane+1) packed bf16.
// Per 16-edge chunk: 1 coalesced idx load -> 16 shfl broadcasts -> 16
// UNCONDITIONAL H-row loads issued back-to-back (out-of-range slots clamped
// to the chunk's last valid edge: safe duplicate addresses) -> masked adds.
// MLP per wave ~16 instead of 1.
__global__ __launch_bounds__(256) void gather_ln_kernel(const int* __restrict__ rowptr,
                                                        const unsigned short* __restrict__ colsrc,
                                                        const unsigned int* __restrict__ Hb,
                                                        const float* __restrict__ dinv,
                                                        const float* __restrict__ bias,
                                                        const float* __restrict__ gamma,
                                                        const float* __restrict__ beta,
                                                        unsigned int* __restrict__ out_bf,
                                                        float* __restrict__ out_f,
                                                        int n, int relu) {
    int wid = threadIdx.x >> 6;
    int lane = threadIdx.x & 63;
    int r = blockIdx.x * 4 + wid;
    if (r >= n) return;

    float di = dinv[r];
    float2 bb = ((const float2*)bias)[lane];
    float2 gg = ((const float2*)gamma)[lane];
    float2 be = ((const float2*)beta)[lane];

    unsigned int su = Hb[(size_t)r * 64 + lane];  // self-loop term (pre-scaled)
    float ax = bf2f_lo(su), ay = bf2f_hi(su);

    int p = rowptr[r];
    int p1 = rowptr[r + 1];
    while (p < p1) {
        int cnt = p1 - p;
        if (cnt > 16) cnt = 16;
        int gi = p + lane;
        gi = gi < p1 ? gi : p1 - 1;          // clamp: valid duplicate
        int idxv = (int)colsrc[gi];          // one coalesced load per chunk

        int s[16];
#pragma unroll
        for (int j = 0; j < 16; ++j) s[j] = __shfl(idxv, j);

        unsigned int h[16];
#pragma unroll
        for (int j = 0; j < 16; ++j) h[j] = Hb[(size_t)s[j] * 64 + lane];

#pragma unroll
        for (int j = 0; j < 16; ++j) {
            bool act = (j < cnt);            // cnt wave-uniform; cndmask, no branch
            ax += act ? bf2f_lo(h[j]) : 0.f;
            ay += act ? bf2f_hi(h[j]) : 0.f;
        }
        p += cnt;
    }

    float vx = ax * di + bb.x;
    float vy = ay * di + bb.y;

    float s1 = vx + vy;
    float s2 = vx * vx + vy * vy;
#pragma unroll
    for (int off = 32; off > 0; off >>= 1) {
        s1 += __shfl_xor(s1, off);
        s2 += __shfl_xor(s2, off);
    }
    float mu = s1 * (1.f / 128.f);
    float var = s2 * (1.f / 128.f) - mu * mu;
    float rstd = rsqrtf(var + LN_EPS);

    float ox = (vx - mu) * rstd * gg.x + be.x;
    float oy = (vy - mu) * rstd * gg.y + be.y;
    if (relu) {
        ox = fmaxf(ox, 0.f);
        oy = fmaxf(oy, 0.f);
    }
    if (out_bf) {
        unsigned int pk = (unsigned int)f2bf(ox) | ((unsigned int)f2bf(oy) << 16);
        out_bf[(size_t)r * 64 + lane] = pk;
    } else {
        ((float2*)out_f)[(size_t)r * 64 + lane] = make_float2(ox, oy);
    }
}

// =============================================================================
extern "C" void kernel_launch(void* const* d_in, const int* in_sizes, int n_in,
                              void* d_out, int out_size, void* d_ws, size_t ws_size,
                              hipStream_t stream) {
    const float* x   = (const float*)d_in[0];
    const int*   ei  = (const int*)d_in[1];
    const float* W1  = (const float*)d_in[2];
    const float* b1  = (const float*)d_in[3];
    const float* g1  = (const float*)d_in[4];
    const float* be1 = (const float*)d_in[5];
    const float* W2  = (const float*)d_in[6];
    const float* b2  = (const float*)d_in[7];
    const float* g2  = (const float*)d_in[8];
    const float* be2 = (const float*)d_in[9];

    int n = in_sizes[0] / DIM;   // 50000
    int E = in_sizes[1] / 2;     // 600000
    const int* src = ei;
    const int* dst = ei + E;

    char* wp = (char*)d_ws;
    auto alloc = [&](size_t bytes) {
        void* p = (void*)wp;
        wp += (bytes + 255) & ~(size_t)255;
        return p;
    };
    float*          dinv   = (float*)alloc((size_t)n * 4);
    int*            counts = (int*)alloc((size_t)n * 4);
    int*            tmp    = (int*)alloc((size_t)n * 4);
    int*            rowptr = (int*)alloc((size_t)(n + 1) * 4);
    int*            cursor = (int*)alloc((size_t)n * 4);
    int*            bsums  = (int*)alloc(64 * 4);
    unsigned short* colsrc = (unsigned short*)alloc((size_t)E * 2);
    unsigned short* xb     = (unsigned short*)alloc((size_t)n * DIM * 2);
    unsigned short* Wt1    = (unsigned short*)alloc(128 * 128 * 2);
    unsigned short* Wt2    = (unsigned short*)alloc(128 * 128 * 2);
    unsigned short* H      = (unsigned short*)alloc((size_t)n * DIM * 2);
    unsigned short* Y1     = (unsigned short*)alloc((size_t)n * DIM * 2);

    hipMemsetAsync(counts, 0, (size_t)n * 4, stream);

    // --- conversions + degree count (one dispatch) ---
    int n4 = n * DIM / 4;
    int nx4b = (n4 + 255) / 256;
    int gE = (E + 255) / 256;
    cvt_count_kernel<<<nx4b + 128 + gE, 256, 0, stream>>>(x, xb, n4, nx4b, W1, W2, Wt1, Wt2,
                                                          dst, counts, E);

    // --- CSR build ---
    int nb1 = (n + 1023) / 1024;  // 49 for n=50000 (must be <= 64)
    scan1_kernel<<<nb1, 256, 0, stream>>>(counts, tmp, bsums, dinv, n);
    scan2_kernel<<<1, 64, 0, stream>>>(bsums, nb1);
    scan3_kernel<<<nb1, 256, 0, stream>>>(tmp, bsums, rowptr, cursor, n, E);
    fill_kernel<<<gE, 256, 0, stream>>>(src, dst, cursor, colsrc, E);

    int ntiles = (n + 15) / 16;
    int gG = (ntiles + 3) / 4;
    int gA = (n + 3) / 4;

    // --- layer 1 ---
    gemm_mfma_kernel<<<gG, 256, 0, stream>>>(xb, Wt1, dinv, H, n, ntiles);
    gather_ln_kernel<<<gA, 256, 0, stream>>>(rowptr, colsrc, (const unsigned int*)H, dinv,
                                             b1, g1, be1, (unsigned int*)Y1, nullptr, n, 1);

    // --- layer 2 ---
    gemm_mfma_kernel<<<gG, 256, 0, stream>>>(Y1, Wt2, dinv, H, n, ntiles);
    gather_ln_kernel<<<gA, 256, 0, stream>>>(rowptr, colsrc, (const unsigned int*)H, dinv,
                                             b2, g2, be2, nullptr, (float*)d_out, n, 0);
}